// Round 11
// baseline (134.646 us; speedup 1.0000x reference)
//
#include <hip/hip_runtime.h>
#include <hip/hip_bf16.h>

#define NN 8192
#define FF 256
#define NEGV -9000000000000000.0f

typedef __bf16 bf16x8 __attribute__((ext_vector_type(8)));
typedef float f32x4 __attribute__((ext_vector_type(4)));
typedef int i32x4 __attribute__((ext_vector_type(4)));

__device__ __forceinline__ void load_lds16(const void* g, void* l) {
  auto gp = (const __attribute__((address_space(1))) void*)(uintptr_t)g;
  auto lp = (__attribute__((address_space(3))) void*)(uint32_t)(uintptr_t)l;
  __builtin_amdgcn_global_load_lds(gp, lp, 16, 0, 0);
}

// ---- kernel 1: inputs -> ibf bf16 [8192,256]; weights -> Wpk bf16 fragment-major ----
// Wpk chunk o (16 B) for o = (((g*16 + fb*4 + w)*8 + ks)*64 + l):
//   holds W row (g*256 + fb*64 + w*16 + (l&15)), f32 cols [(l>>4)*8 + ks*32, +8) as bf16.
// g 0..2 = W_ih gates r,z,n; g 3..5 = W_hh gates r,z,n.
__global__ __launch_bounds__(256) void k_convert(const float* __restrict__ inputs,
                                                 const float* __restrict__ Wih,
                                                 const float* __restrict__ Whh,
                                                 __hip_bfloat16* __restrict__ ibf,
                                                 __hip_bfloat16* __restrict__ Wc) {
  const int gid = blockIdx.x * 256 + threadIdx.x;   // 311296 threads total
  const float* src;
  __hip_bfloat16* dst;
  if (gid < 262144) {                               // inputs: 8 elems/thread
    src = inputs + (size_t)gid * 8;
    dst = ibf + (size_t)gid * 8;
  } else {
    const int o = gid - 262144;                     // packed chunk 0..49151
    const int l = o & 63;
    const int ks = (o >> 6) & 7;
    const int w = (o >> 9) & 3;
    const int fbb = (o >> 11) & 3;
    const int g = o >> 13;                          // 0..5
    const int row = g * 256 + fbb * 64 + w * 16 + (l & 15);
    const int col = (l >> 4) * 8 + ks * 32;
    src = (row < 768) ? (Wih + (size_t)row * FF + col)
                      : (Whh + (size_t)(row - 768) * FF + col);
    dst = Wc + (size_t)o * 8;
  }
  const float4 v0 = *(const float4*)src;
  const float4 v1 = *(const float4*)(src + 4);
  union { __hip_bfloat16 h[8]; uint4 u; } t;
  t.h[0] = __float2bfloat16(v0.x); t.h[1] = __float2bfloat16(v0.y);
  t.h[2] = __float2bfloat16(v0.z); t.h[3] = __float2bfloat16(v0.w);
  t.h[4] = __float2bfloat16(v1.x); t.h[5] = __float2bfloat16(v1.y);
  t.h[6] = __float2bfloat16(v1.z); t.h[7] = __float2bfloat16(v1.w);
  *(uint4*)dst = t.u;
}

// ---- kernel 2: fused gather + dual GEMM + GRU + dot-reduce -> partial s1, s2 ----
// Block = 16 rows x 64 features (fb = blockIdx.y). Wave w covers features fb*64 + w*16 + (l&15).
// Two independent MFMA chains (ih via axf, hh via ahf) interleaved.
__global__ __launch_bounds__(256) void k_gru(const __hip_bfloat16* __restrict__ ibf,
                                             const __hip_bfloat16* __restrict__ Wpk,
                                             const float* __restrict__ inputs,
                                             const int* __restrict__ nbr,
                                             const float* __restrict__ b_ih,
                                             const float* __restrict__ b_hh,
                                             const float* __restrict__ a,
                                             float* __restrict__ p1a,
                                             float* __restrict__ p2a) {
  __shared__ __align__(16) __hip_bfloat16 Ax[16 * 256];   // 8 KB, xor-swizzled chunks
  __shared__ __align__(16) __hip_bfloat16 Ah[16 * 256];   // 8 KB
  __shared__ int hrow_s[16];
  __shared__ float r1[4][16], r2[4][16];
  const int rb = blockIdx.x * 16;
  const int fb = blockIdx.y;
  const int tid = threadIdx.x;
  const int w = tid >> 6, l = tid & 63;
  const int fl = l & 15, q = l >> 4;

  if (tid < 16) hrow_s[tid] = nbr[2 * (rb + tid)];

  // Stage 16 gathered rows of x and h into LDS. Wave w stages rows w*4..w*4+3.
  // LDS dest linear; global src pre-swizzled: LDS slot (r, cs) holds global chunk (cs ^ (r&7)).
#pragma unroll
  for (int j = 0; j < 2; ++j) {
    const int r = w * 4 + j * 2 + (l >> 5);
    const int cs = l & 31;
    const int gc = cs ^ (r & 7);
    const int xr = nbr[2 * (rb + r) + 1];
    const int hr_ = nbr[2 * (rb + r)];
    load_lds16((const char*)(ibf + (size_t)xr * FF) + gc * 16,
               (char*)Ax + (w * 4 + j * 2) * 512);
    load_lds16((const char*)(ibf + (size_t)hr_ * FF) + gc * 16,
               (char*)Ah + (w * 4 + j * 2) * 512);
  }
  __syncthreads();

  const int f = fb * 64 + w * 16 + fl;
  const float bir = b_ih[f], biz = b_ih[256 + f], bin_ = b_ih[512 + f];
  const float bhr = b_hh[f], bhz = b_hh[256 + f], bhn = b_hh[512 + f];
  const float a1f = a[f], a2f = a[256 + f];

  f32x4 acc[6];
#pragma unroll
  for (int g = 0; g < 6; ++g) acc[g] = (f32x4){0, 0, 0, 0};

  // A-frags (swizzled read): row = fl, chunk c = ks*4+q, slot = c ^ (fl&7)
  bf16x8 axf[8], ahf[8];
#pragma unroll
  for (int ks = 0; ks < 8; ++ks) {
    const int c = ks * 4 + q;
    axf[ks] = *(const bf16x8*)((const char*)Ax + fl * 512 + (c ^ (fl & 7)) * 16);
    ahf[ks] = *(const bf16x8*)((const char*)Ah + fl * 512 + (c ^ (fl & 7)) * 16);
  }
#pragma unroll
  for (int g = 0; g < 3; ++g) {
    const int bi = ((g * 16 + fb * 4 + w) * 8) * 64 + l;         // packed chunk idx (ih)
    const int bh = (((3 + g) * 16 + fb * 4 + w) * 8) * 64 + l;   // packed chunk idx (hh)
#pragma unroll
    for (int ks = 0; ks < 8; ++ks) {
      const bf16x8 bfi = *(const bf16x8*)(Wpk + (size_t)(bi + ks * 64) * 8);
      const bf16x8 bfh = *(const bf16x8*)(Wpk + (size_t)(bh + ks * 64) * 8);
      acc[g]     = __builtin_amdgcn_mfma_f32_16x16x32_bf16(axf[ks], bfi, acc[g], 0, 0, 0);
      acc[3 + g] = __builtin_amdgcn_mfma_f32_16x16x32_bf16(ahf[ks], bfh, acc[3 + g], 0, 0, 0);
    }
  }

  // GRU epilogue (C/D: col=lane&15, row=q*4+j), rows 0..15
  float p1[4], p2[4];
#pragma unroll
  for (int j = 0; j < 4; ++j) {
    const int row = q * 4 + j;
    const float ir = acc[0][j] + bir;
    const float iz = acc[1][j] + biz;
    const float in_ = acc[2][j] + bin_;
    const float hrv = acc[3][j] + bhr;
    const float hzv = acc[4][j] + bhz;
    const float hnv = acc[5][j] + bhn;
    const float r_ = 1.f / (1.f + __expf(-(ir + hrv)));
    const float z_ = 1.f / (1.f + __expf(-(iz + hzv)));
    const float n_ = tanhf(in_ + r_ * hnv);
    const float hval = inputs[(size_t)hrow_s[row] * FF + f];
    const float o = (1.f - z_) * n_ + z_ * hval;
    p1[j] = o * a1f;
    p2[j] = o * a2f;
  }

#pragma unroll
  for (int j = 0; j < 4; ++j) {
#pragma unroll
    for (int off = 1; off < 16; off <<= 1) {
      p1[j] += __shfl_xor(p1[j], off);
      p2[j] += __shfl_xor(p2[j], off);
    }
  }
  if (fl == 0) {
#pragma unroll
    for (int j = 0; j < 4; ++j) {
      r1[w][q * 4 + j] = p1[j];
      r2[w][q * 4 + j] = p2[j];
    }
  }
  __syncthreads();
  if (tid < 16) {
    p1a[fb * NN + rb + tid] = r1[0][tid] + r1[1][tid] + r1[2][tid] + r1[3][tid];
  } else if (tid < 32) {
    const int t2 = tid - 16;
    p2a[fb * NN + rb + t2] = r2[0][t2] + r2[1][t2] + r2[2][t2] + r2[3][t2];
  }
}

// ---- kernel 3: sum the 4 feature-block partials -> s1, s2 (in d_ws) ----
__global__ __launch_bounds__(256) void k_reduce(const float* __restrict__ p1a,
                                                const float* __restrict__ p2a,
                                                float* __restrict__ s1,
                                                float* __restrict__ s2) {
  const int i = blockIdx.x * 256 + threadIdx.x;   // 8192 threads
  s1[i] = p1a[i] + p1a[NN + i] + p1a[2 * NN + i] + p1a[3 * NN + i];
  s2[i] = p2a[i] + p2a[NN + i] + p2a[2 * NN + i] + p2a[3 * NN + i];
}

// ---- kernel 4: masked row softmax, 1024 threads x 8 elems/thread, max occupancy ----
// no-max (exp-safe): exp(NEGV)==0 handles the mask exactly. Recompute exps in store
// pass. Held state: a4[2 int4] + sv[2 f32x4] = 16 VGPR -> target <=64 VGPR,
// launch_bounds(1024,8) = 2 blocks/CU = 32 waves/CU (hardware max TLP).
__global__ __launch_bounds__(1024, 8) void k_softmax(const int* __restrict__ adj,
                                                     const float* __restrict__ s1,
                                                     const float* __restrict__ s2,
                                                     float* __restrict__ out) {
  __shared__ float red[16];
  const int row = blockIdx.x;
  const int t = threadIdx.x;                      // 0..1023, handles cols 8t..8t+7
  const i32x4* adjv = (const i32x4*)(adj + (size_t)row * NN) + t * 2;
  i32x4 a4[2];
  a4[0] = __builtin_nontemporal_load(adjv);
  a4[1] = __builtin_nontemporal_load(adjv + 1);
  f32x4 sv[2];
  sv[0] = *(const f32x4*)(s2 + t * 8);
  sv[1] = *(const f32x4*)(s2 + t * 8 + 4);
  const float s1v = s1[row];

  float tsum = 0.f;
#pragma unroll
  for (int k = 0; k < 2; ++k) {
#pragma unroll
    for (int c = 0; c < 4; ++c) {
      float x = s1v + sv[k][c];
      x = (x > 0.f) ? x : 0.2f * x;
      x = (a4[k][c] > 0) ? x : NEGV;
      tsum += __expf(x);             // exp(NEGV) == 0 handles the mask exactly
    }
  }
#pragma unroll
  for (int off = 32; off; off >>= 1) tsum += __shfl_xor(tsum, off);
  if ((t & 63) == 0) red[t >> 6] = tsum;
  __syncthreads();
  float tot = 0.f;
#pragma unroll
  for (int i = 0; i < 16; ++i) tot += red[i];
  const float inv = 1.f / tot;
  float* orow = out + (size_t)row * NN + t * 8;
#pragma unroll
  for (int k = 0; k < 2; ++k) {
    f32x4 o;
#pragma unroll
    for (int c = 0; c < 4; ++c) {
      float x = s1v + sv[k][c];
      x = (x > 0.f) ? x : 0.2f * x;
      x = (a4[k][c] > 0) ? x : NEGV;
      o[c] = __expf(x) * inv;        // bitwise-identical exp to pass 1
    }
    __builtin_nontemporal_store(o, (f32x4*)(orow + k * 4));
  }
}

extern "C" void kernel_launch(void* const* d_in, const int* in_sizes, int n_in,
                              void* d_out, int out_size, void* d_ws, size_t ws_size,
                              hipStream_t stream) {
  const float* inputs = (const float*)d_in[0];
  const float* W_ih   = (const float*)d_in[1];
  const float* W_hh   = (const float*)d_in[2];
  const float* b_ih   = (const float*)d_in[3];
  const float* b_hh   = (const float*)d_in[4];
  const float* a      = (const float*)d_in[5];
  const int*   nbr    = (const int*)d_in[6];
  const int*   adj    = (const int*)d_in[7];
  float* out = (float*)d_out;

  // Scratch inside d_out (fully overwritten by k_softmax at the end):
  //   [64MB, 68MB): ibf bf16 [8192, 256]
  //   [80MB, ..)  : Wpk bf16 packed weights (1.5 MB)
  //   [96MB, ..)  : p1a f32 [4][8192]; p2a right after (128 KB each)
  __hip_bfloat16* ibf = (__hip_bfloat16*)((char*)d_out + (64u << 20));
  __hip_bfloat16* Wpk = (__hip_bfloat16*)((char*)d_out + (80u << 20));
  float* p1a = (float*)((char*)d_out + (96u << 20));
  float* p2a = p1a + 4 * NN;
  float* s1 = (float*)d_ws;        // 32 KB
  float* s2 = s1 + NN;             // 32 KB

  k_convert<<<1216, 256, 0, stream>>>(inputs, W_ih, W_hh, ibf, Wpk);
  k_gru<<<dim3(512, 4), 256, 0, stream>>>(ibf, Wpk, inputs, nbr, b_ih, b_hh, a, p1a, p2a);
  k_reduce<<<32, 256, 0, stream>>>(p1a, p2a, s1, s2);
  k_softmax<<<NN, 1024, 0, stream>>>(adj, s1, s2, out);
}

// Round 12
// 121.569 us; speedup vs baseline: 1.1076x; 1.1076x over previous
//
#include <hip/hip_runtime.h>
#include <hip/hip_bf16.h>

#define NN 8192
#define FF 256
#define NEGV -9000000000000000.0f

typedef __bf16 bf16x8 __attribute__((ext_vector_type(8)));
typedef float f32x4 __attribute__((ext_vector_type(4)));
typedef int i32x4 __attribute__((ext_vector_type(4)));

// ---- kernel 1: pack W_ih/W_hh -> Wpk bf16 fragment-major (weights only) ----
// Wpk chunk o (16 B) for o = (((g*16 + fb*4 + w)*8 + ks)*64 + l):
//   holds W row (g*256 + fb*64 + w*16 + (l&15)), f32 cols [(l>>4)*8 + ks*32, +8) as bf16.
// g 0..2 = W_ih gates r,z,n; g 3..5 = W_hh gates r,z,n.
__global__ __launch_bounds__(256) void k_pack(const float* __restrict__ Wih,
                                              const float* __restrict__ Whh,
                                              __hip_bfloat16* __restrict__ Wc) {
  const int o = blockIdx.x * 256 + threadIdx.x;     // 49152 chunks
  const int l = o & 63;
  const int ks = (o >> 6) & 7;
  const int w = (o >> 9) & 3;
  const int fbb = (o >> 11) & 3;
  const int g = o >> 13;                            // 0..5
  const int row = g * 256 + fbb * 64 + w * 16 + (l & 15);
  const int col = (l >> 4) * 8 + ks * 32;
  const float* src = (row < 768) ? (Wih + (size_t)row * FF + col)
                                 : (Whh + (size_t)(row - 768) * FF + col);
  const float4 v0 = *(const float4*)src;
  const float4 v1 = *(const float4*)(src + 4);
  union { __hip_bfloat16 h[8]; uint4 u; } t;
  t.h[0] = __float2bfloat16(v0.x); t.h[1] = __float2bfloat16(v0.y);
  t.h[2] = __float2bfloat16(v0.z); t.h[3] = __float2bfloat16(v0.w);
  t.h[4] = __float2bfloat16(v1.x); t.h[5] = __float2bfloat16(v1.y);
  t.h[6] = __float2bfloat16(v1.z); t.h[7] = __float2bfloat16(v1.w);
  *(uint4*)(Wc + (size_t)o * 8) = t.u;
}

// ---- kernel 2: fused gather(f32)+convert + dual GEMM + GRU + dot-reduce -> partials ----
// Block = 16 rows x 64 features (fb = blockIdx.y). Wave w covers features fb*64 + w*16 + (l&15).
// Staging: gather f32 rows straight from `inputs` (L3-resident, 32 MB), convert in-register,
// swizzled ds_write_b128 (LDS slot (r, cs) holds global chunk cs ^ (r&7), chunk = 8 bf16).
// Read side identical to the proven r6 k_gru.
__global__ __launch_bounds__(256) void k_gru(const __hip_bfloat16* __restrict__ Wpk,
                                             const float* __restrict__ inputs,
                                             const int* __restrict__ nbr,
                                             const float* __restrict__ b_ih,
                                             const float* __restrict__ b_hh,
                                             const float* __restrict__ a,
                                             float* __restrict__ p1a,
                                             float* __restrict__ p2a) {
  __shared__ __align__(16) __hip_bfloat16 Ax[16 * 256];   // 8 KB, xor-swizzled chunks
  __shared__ __align__(16) __hip_bfloat16 Ah[16 * 256];   // 8 KB
  __shared__ int hrow_s[16];
  __shared__ float r1[4][16], r2[4][16];
  const int rb = blockIdx.x * 16;
  const int fb = blockIdx.y;
  const int tid = threadIdx.x;
  const int w = tid >> 6, l = tid & 63;
  const int fl = l & 15, q = l >> 4;

  if (tid < 16) hrow_s[tid] = nbr[2 * (rb + tid)];

  // Wave w stages rows w*4..w*4+3: 2 issues x 2 rows; lane handles chunk gc = l&31 (16 B bf16).
#pragma unroll
  for (int j = 0; j < 2; ++j) {
    const int r = w * 4 + j * 2 + (l >> 5);
    const int gc = l & 31;
    const int xr = nbr[2 * (rb + r) + 1];
    const int hr_ = nbr[2 * (rb + r)];
    const float4 xv0 = *(const float4*)(inputs + (size_t)xr * FF + gc * 8);
    const float4 xv1 = *(const float4*)(inputs + (size_t)xr * FF + gc * 8 + 4);
    const float4 hv0 = *(const float4*)(inputs + (size_t)hr_ * FF + gc * 8);
    const float4 hv1 = *(const float4*)(inputs + (size_t)hr_ * FF + gc * 8 + 4);
    union { __hip_bfloat16 hh[8]; uint4 u; } tx, th;
    tx.hh[0] = __float2bfloat16(xv0.x); tx.hh[1] = __float2bfloat16(xv0.y);
    tx.hh[2] = __float2bfloat16(xv0.z); tx.hh[3] = __float2bfloat16(xv0.w);
    tx.hh[4] = __float2bfloat16(xv1.x); tx.hh[5] = __float2bfloat16(xv1.y);
    tx.hh[6] = __float2bfloat16(xv1.z); tx.hh[7] = __float2bfloat16(xv1.w);
    th.hh[0] = __float2bfloat16(hv0.x); th.hh[1] = __float2bfloat16(hv0.y);
    th.hh[2] = __float2bfloat16(hv0.z); th.hh[3] = __float2bfloat16(hv0.w);
    th.hh[4] = __float2bfloat16(hv1.x); th.hh[5] = __float2bfloat16(hv1.y);
    th.hh[6] = __float2bfloat16(hv1.z); th.hh[7] = __float2bfloat16(hv1.w);
    *(uint4*)((char*)Ax + r * 512 + (gc ^ (r & 7)) * 16) = tx.u;
    *(uint4*)((char*)Ah + r * 512 + (gc ^ (r & 7)) * 16) = th.u;
  }
  __syncthreads();

  const int f = fb * 64 + w * 16 + fl;
  const float bir = b_ih[f], biz = b_ih[256 + f], bin_ = b_ih[512 + f];
  const float bhr = b_hh[f], bhz = b_hh[256 + f], bhn = b_hh[512 + f];
  const float a1f = a[f], a2f = a[256 + f];

  f32x4 acc[6];
#pragma unroll
  for (int g = 0; g < 6; ++g) acc[g] = (f32x4){0, 0, 0, 0};

  // A-frags (swizzled read): row = fl, chunk c = ks*4+q, slot = c ^ (fl&7)
  bf16x8 axf[8], ahf[8];
#pragma unroll
  for (int ks = 0; ks < 8; ++ks) {
    const int c = ks * 4 + q;
    axf[ks] = *(const bf16x8*)((const char*)Ax + fl * 512 + (c ^ (fl & 7)) * 16);
    ahf[ks] = *(const bf16x8*)((const char*)Ah + fl * 512 + (c ^ (fl & 7)) * 16);
  }
#pragma unroll
  for (int g = 0; g < 3; ++g) {
    const int bi = ((g * 16 + fb * 4 + w) * 8) * 64 + l;         // packed chunk idx (ih)
    const int bh = (((3 + g) * 16 + fb * 4 + w) * 8) * 64 + l;   // packed chunk idx (hh)
#pragma unroll
    for (int ks = 0; ks < 8; ++ks) {
      const bf16x8 bfi = *(const bf16x8*)(Wpk + (size_t)(bi + ks * 64) * 8);
      const bf16x8 bfh = *(const bf16x8*)(Wpk + (size_t)(bh + ks * 64) * 8);
      acc[g]     = __builtin_amdgcn_mfma_f32_16x16x32_bf16(axf[ks], bfi, acc[g], 0, 0, 0);
      acc[3 + g] = __builtin_amdgcn_mfma_f32_16x16x32_bf16(ahf[ks], bfh, acc[3 + g], 0, 0, 0);
    }
  }

  // GRU epilogue (C/D: col=lane&15, row=q*4+j), rows 0..15
  float p1[4], p2[4];
#pragma unroll
  for (int j = 0; j < 4; ++j) {
    const int row = q * 4 + j;
    const float ir = acc[0][j] + bir;
    const float iz = acc[1][j] + biz;
    const float in_ = acc[2][j] + bin_;
    const float hrv = acc[3][j] + bhr;
    const float hzv = acc[4][j] + bhz;
    const float hnv = acc[5][j] + bhn;
    const float r_ = 1.f / (1.f + __expf(-(ir + hrv)));
    const float z_ = 1.f / (1.f + __expf(-(iz + hzv)));
    const float n_ = tanhf(in_ + r_ * hnv);
    const float hval = inputs[(size_t)hrow_s[row] * FF + f];
    const float o = (1.f - z_) * n_ + z_ * hval;
    p1[j] = o * a1f;
    p2[j] = o * a2f;
  }

#pragma unroll
  for (int j = 0; j < 4; ++j) {
#pragma unroll
    for (int off = 1; off < 16; off <<= 1) {
      p1[j] += __shfl_xor(p1[j], off);
      p2[j] += __shfl_xor(p2[j], off);
    }
  }
  if (fl == 0) {
#pragma unroll
    for (int j = 0; j < 4; ++j) {
      r1[w][q * 4 + j] = p1[j];
      r2[w][q * 4 + j] = p2[j];
    }
  }
  __syncthreads();
  if (tid < 16) {
    p1a[fb * NN + rb + tid] = r1[0][tid] + r1[1][tid] + r1[2][tid] + r1[3][tid];
  } else if (tid < 32) {
    const int t2 = tid - 16;
    p2a[fb * NN + rb + t2] = r2[0][t2] + r2[1][t2] + r2[2][t2] + r2[3][t2];
  }
}

// ---- kernel 3: sum the 4 feature-block partials -> s1, s2 (in d_ws) ----
__global__ __launch_bounds__(256) void k_reduce(const float* __restrict__ p1a,
                                                const float* __restrict__ p2a,
                                                float* __restrict__ s1,
                                                float* __restrict__ s2) {
  const int i = blockIdx.x * 256 + threadIdx.x;   // 8192 threads
  s1[i] = p1a[i] + p1a[NN + i] + p1a[2 * NN + i] + p1a[3 * NN + i];
  s2[i] = p2a[i] + p2a[NN + i] + p2a[2 * NN + i] + p2a[3 * NN + i];
}

// ---- kernel 4: masked row softmax, no-max (exp-safe), RECOMPUTE variant (r6 best) ----
// Holds only a4[8]+sv[8] across the barrier (~80 VGPR); exp recomputed in the store
// pass. launch_bounds(256,5) -> 5 blocks/CU resident memory streams.
__global__ __launch_bounds__(256, 5) void k_softmax(const int* __restrict__ adj,
                                                    const float* __restrict__ s1,
                                                    const float* __restrict__ s2,
                                                    float* __restrict__ out) {
  __shared__ float red[4];
  const int row = blockIdx.x;
  const int t = threadIdx.x;
  const i32x4* adjv = (const i32x4*)(adj + (size_t)row * NN);
  i32x4 a4[8];
#pragma unroll
  for (int k = 0; k < 8; ++k) a4[k] = __builtin_nontemporal_load(adjv + k * 256 + t);
  f32x4 sv[8];
#pragma unroll
  for (int k = 0; k < 8; ++k) sv[k] = *(const f32x4*)(s2 + (k * 256 + t) * 4);
  const float s1v = s1[row];

  float tsum = 0.f;
#pragma unroll
  for (int k = 0; k < 8; ++k) {
#pragma unroll
    for (int c = 0; c < 4; ++c) {
      float x = s1v + sv[k][c];
      x = (x > 0.f) ? x : 0.2f * x;
      x = (a4[k][c] > 0) ? x : NEGV;
      tsum += __expf(x);             // exp(NEGV) == 0 handles the mask exactly
    }
  }
#pragma unroll
  for (int off = 32; off; off >>= 1) tsum += __shfl_xor(tsum, off);
  if ((t & 63) == 0) red[t >> 6] = tsum;
  __syncthreads();
  const float inv = 1.f / (red[0] + red[1] + red[2] + red[3]);
  float* orow = out + (size_t)row * NN;
#pragma unroll
  for (int k = 0; k < 8; ++k) {
    const int v = k * 256 + t;
    f32x4 o;
#pragma unroll
    for (int c = 0; c < 4; ++c) {
      float x = s1v + sv[k][c];
      x = (x > 0.f) ? x : 0.2f * x;
      x = (a4[k][c] > 0) ? x : NEGV;
      o[c] = __expf(x) * inv;        // bitwise-identical exp to pass 1
    }
    __builtin_nontemporal_store(o, (f32x4*)(orow + v * 4));
  }
}

extern "C" void kernel_launch(void* const* d_in, const int* in_sizes, int n_in,
                              void* d_out, int out_size, void* d_ws, size_t ws_size,
                              hipStream_t stream) {
  const float* inputs = (const float*)d_in[0];
  const float* W_ih   = (const float*)d_in[1];
  const float* W_hh   = (const float*)d_in[2];
  const float* b_ih   = (const float*)d_in[3];
  const float* b_hh   = (const float*)d_in[4];
  const float* a      = (const float*)d_in[5];
  const int*   nbr    = (const int*)d_in[6];
  const int*   adj    = (const int*)d_in[7];
  float* out = (float*)d_out;

  // Scratch inside d_out (fully overwritten by k_softmax at the end):
  //   [80MB, ..) : Wpk bf16 packed weights (1.5 MB)
  //   [96MB, ..) : p1a f32 [4][8192]; p2a right after (128 KB each)
  __hip_bfloat16* Wpk = (__hip_bfloat16*)((char*)d_out + (80u << 20));
  float* p1a = (float*)((char*)d_out + (96u << 20));
  float* p2a = p1a + 4 * NN;
  float* s1 = (float*)d_ws;        // 32 KB
  float* s2 = s1 + NN;             // 32 KB

  k_pack<<<192, 256, 0, stream>>>(W_ih, W_hh, Wpk);
  k_gru<<<dim3(512, 4), 256, 0, stream>>>(Wpk, inputs, nbr, b_ih, b_hh, a, p1a, p2a);
  k_reduce<<<32, 256, 0, stream>>>(p1a, p2a, s1, s2);
  k_softmax<<<NN, 256, 0, stream>>>(adj, s1, s2, out);
}